// Round 4
// baseline (269.663 us; speedup 1.0000x reference)
//
#include <hip/hip_runtime.h>

// Problem constants
#define BB 2
#define TT 2048
#define CC 1024
#define NH 16
#define HD 64

typedef __attribute__((ext_vector_type(8))) short bf16x8;
typedef __attribute__((ext_vector_type(4))) float floatx4;

__device__ __forceinline__ unsigned short f2bf(float f) {
    union { float f; unsigned int u; } v; v.f = f;
    unsigned int u = v.u;
    u = (u + 0x7fffu + ((u >> 16) & 1u)) >> 16;   // RNE
    return (unsigned short)u;
}

typedef __attribute__((address_space(3))) unsigned char* lds_ptr_t;
typedef const __attribute__((address_space(1))) unsigned char* glob_ptr_t;
__device__ __forceinline__ void gll16(const void* g, void* l) {
    __builtin_amdgcn_global_load_lds((glob_ptr_t)g, (lds_ptr_t)l, 16, 0, 0);
}

// ---------------- fused cast fp32 -> bf16 for x, Wq|Wk|Wv, Wo ----------------
__global__ __launch_bounds__(256) void cast_all_k(const float* __restrict__ x,
                                                  const float* __restrict__ wq,
                                                  const float* __restrict__ wk,
                                                  const float* __restrict__ wv,
                                                  const float* __restrict__ wo,
                                                  unsigned short* __restrict__ xb,
                                                  unsigned short* __restrict__ wqkvb,
                                                  unsigned short* __restrict__ wob) {
    int i = blockIdx.x * 256 + threadIdx.x;   // float4 index, 0..2097151
    const float* src;
    unsigned short* dst;
    if (i < 1048576) {
        src = x + (size_t)i * 4;
        dst = xb + (size_t)i * 4;
    } else {
        int w   = (i - 1048576) >> 18;        // 0..3
        int off = (i - 1048576) & 262143;
        const float* s0 = (w == 0) ? wq : (w == 1) ? wk : (w == 2) ? wv : wo;
        unsigned short* d0 = (w == 3) ? wob : (wqkvb + (size_t)w * 1048576);
        src = s0 + (size_t)off * 4;
        dst = d0 + (size_t)off * 4;
    }
    float4 v = *(const float4*)src;
    ushort4 o;
    o.x = f2bf(v.x); o.y = f2bf(v.y); o.z = f2bf(v.z); o.w = f2bf(v.w);
    *(ushort4*)dst = o;
}

// ---------------- m97-style GEMM: C[M,N] fp32 = A[M,K] * Bt[N,K]^T (out-proj) ----------------
__global__ __launch_bounds__(256) void gemm128_k(const unsigned short* __restrict__ A,
                                                 const unsigned short* __restrict__ Bt,
                                                 float* __restrict__ C, int M, int N, int K) {
    __shared__ __align__(16) unsigned short As[128][32];
    __shared__ __align__(16) unsigned short Bs[128][32];
    const int tid  = threadIdx.x;
    const int wave = tid >> 6;
    const int lane = tid & 63;
    const int quad = lane >> 4;
    const int l16  = lane & 15;
    const int wr = (wave >> 1) * 64;
    const int wc = (wave & 1) * 64;
    const int row0 = blockIdx.y * 128;
    const int col0 = blockIdx.x * 128;
    const int srow = tid >> 2;
    const int scol = (tid & 3) * 8;

    const unsigned short* Ap0 = A  + (size_t)(row0 + srow) * K + scol;
    const unsigned short* Ap1 = A  + (size_t)(row0 + 64 + srow) * K + scol;
    const unsigned short* Bp0 = Bt + (size_t)(col0 + srow) * K + scol;
    const unsigned short* Bp1 = Bt + (size_t)(col0 + 64 + srow) * K + scol;

    floatx4 acc[4][4];
    #pragma unroll
    for (int i = 0; i < 4; i++)
        #pragma unroll
        for (int j = 0; j < 4; j++) acc[i][j] = (floatx4){0.f, 0.f, 0.f, 0.f};

    for (int k0 = 0; k0 < K; k0 += 32) {
        __syncthreads();
        gll16(Ap0 + k0, &As[srow][scol]);
        gll16(Ap1 + k0, &As[64 + srow][scol]);
        gll16(Bp0 + k0, &Bs[srow][scol]);
        gll16(Bp1 + k0, &Bs[64 + srow][scol]);
        __syncthreads();
        bf16x8 af[4], bfr[4];
        #pragma unroll
        for (int i = 0; i < 4; i++) af[i]  = *(const bf16x8*)&As[wr + 16 * i + l16][quad * 8];
        #pragma unroll
        for (int j = 0; j < 4; j++) bfr[j] = *(const bf16x8*)&Bs[wc + 16 * j + l16][quad * 8];
        #pragma unroll
        for (int i = 0; i < 4; i++)
            #pragma unroll
            for (int j = 0; j < 4; j++)
                acc[i][j] = __builtin_amdgcn_mfma_f32_16x16x32_bf16(af[i], bfr[j], acc[i][j], 0, 0, 0);
    }

    #pragma unroll
    for (int i = 0; i < 4; i++)
        #pragma unroll
        for (int j = 0; j < 4; j++)
            #pragma unroll
            for (int r = 0; r < 4; r++) {
                int row = row0 + wr + 16 * i + quad * 4 + r;
                int col = col0 + wc + 16 * j + l16;
                C[(size_t)row * N + col] = acc[i][j][r];
            }
}

// ---------------- QKV GEMM with fused RoPE epilogue ----------------
// A = x bf16 [4096,1024], Bt = Wq|Wk|Wv bf16 [3072,1024].
// Epilogue: Q/K cols get RoPE (pairs (d,d+32) are acc[i][j] / acc[i][j+2], register-local),
// written bf16 to Qb/Kb [BH,T,D]; V cols written bf16 to Vb [BH,T,D].
__global__ __launch_bounds__(256) void gemm_qkv_k(const unsigned short* __restrict__ A,
                                                  const unsigned short* __restrict__ Bt,
                                                  unsigned short* __restrict__ Qb,
                                                  unsigned short* __restrict__ Kb,
                                                  unsigned short* __restrict__ Vb) {
    __shared__ __align__(16) unsigned short As[128][32];
    __shared__ __align__(16) unsigned short Bs[128][32];
    const int K = 1024;
    const int tid  = threadIdx.x;
    const int wave = tid >> 6;
    const int lane = tid & 63;
    const int quad = lane >> 4;
    const int l16  = lane & 15;
    const int wr = (wave >> 1) * 64;
    const int wc = (wave & 1) * 64;
    const int row0 = blockIdx.y * 128;
    const int col0 = blockIdx.x * 128;
    const int srow = tid >> 2;
    const int scol = (tid & 3) * 8;

    const unsigned short* Ap0 = A  + (size_t)(row0 + srow) * K + scol;
    const unsigned short* Ap1 = A  + (size_t)(row0 + 64 + srow) * K + scol;
    const unsigned short* Bp0 = Bt + (size_t)(col0 + srow) * K + scol;
    const unsigned short* Bp1 = Bt + (size_t)(col0 + 64 + srow) * K + scol;

    floatx4 acc[4][4];
    #pragma unroll
    for (int i = 0; i < 4; i++)
        #pragma unroll
        for (int j = 0; j < 4; j++) acc[i][j] = (floatx4){0.f, 0.f, 0.f, 0.f};

    for (int k0 = 0; k0 < K; k0 += 32) {
        __syncthreads();
        gll16(Ap0 + k0, &As[srow][scol]);
        gll16(Ap1 + k0, &As[64 + srow][scol]);
        gll16(Bp0 + k0, &Bs[srow][scol]);
        gll16(Bp1 + k0, &Bs[64 + srow][scol]);
        __syncthreads();
        bf16x8 af[4], bfr[4];
        #pragma unroll
        for (int i = 0; i < 4; i++) af[i]  = *(const bf16x8*)&As[wr + 16 * i + l16][quad * 8];
        #pragma unroll
        for (int j = 0; j < 4; j++) bfr[j] = *(const bf16x8*)&Bs[wc + 16 * j + l16][quad * 8];
        #pragma unroll
        for (int i = 0; i < 4; i++)
            #pragma unroll
            for (int j = 0; j < 4; j++)
                acc[i][j] = __builtin_amdgcn_mfma_f32_16x16x32_bf16(af[i], bfr[j], acc[i][j], 0, 0, 0);
    }

    const int colw = col0 + wc;           // wave's 64-col stripe base (multiple of 64)
    const int sect = colw >> 10;          // 0=Q, 1=K, 2=V
    const int h    = (colw & 1023) >> 6;  // head

    if (sect == 2) {
        #pragma unroll
        for (int i = 0; i < 4; i++)
            #pragma unroll
            for (int r = 0; r < 4; r++) {
                int row = row0 + wr + 16 * i + quad * 4 + r;
                int t = row & (TT - 1);
                size_t base = ((size_t)((row >> 11) * NH + h) * TT + t) * 64;
                #pragma unroll
                for (int j = 0; j < 4; j++)
                    Vb[base + 16 * j + l16] = f2bf(acc[i][j][r]);
            }
    } else {
        unsigned short* dst = sect ? Kb : Qb;
        // inv_freq(d)/2pi for d = l16, 16+l16 (pair index = d, pairs with d+32)
        const float C1 = 0.41524101186092f;        // log2(10000)/32
        const float I2PI = 0.15915494309189535f;
        float invf0 = __builtin_amdgcn_exp2f(-(float)l16 * C1) * I2PI;
        float invf1 = __builtin_amdgcn_exp2f(-(float)(16 + l16) * C1) * I2PI;
        #pragma unroll
        for (int i = 0; i < 4; i++) {
            #pragma unroll
            for (int r = 0; r < 4; r++) {
                int row = row0 + wr + 16 * i + quad * 4 + r;
                int t = row & (TT - 1);
                size_t base = ((size_t)((row >> 11) * NH + h) * TT + t) * 64;
                #pragma unroll
                for (int jj = 0; jj < 2; jj++) {
                    float rev = (float)t * (jj ? invf1 : invf0);
                    rev -= floorf(rev);                 // reduce to [0,1) revolutions
                    float ang = rev * 6.2831853071796f;
                    float c = __cosf(ang), s = __sinf(ang);
                    float v1 = acc[i][jj][r], v2 = acc[i][jj + 2][r];
                    dst[base + 16 * jj + l16]      = f2bf(v1 * c - v2 * s);
                    dst[base + 16 * jj + 32 + l16] = f2bf(v2 * c + v1 * s);
                }
            }
        }
    }
}

// ---------------- V transpose: Vb [BH,T,D] -> Vt [BH,D,T], key-permuted pi(16c+l)=4l+c ----------------
__global__ __launch_bounds__(256) void vtr_k(const unsigned short* __restrict__ Vb,
                                             unsigned short* __restrict__ Vt) {
    __shared__ __align__(16) unsigned short Vsh[64][70];
    const int tid = threadIdx.x;
    const int tt = blockIdx.x;    // t-tile 0..31
    const int bh = blockIdx.y;    // 0..31
    const int sr = tid >> 2;
    const int sc = (tid & 3) * 16;
    const unsigned short* src = Vb + ((size_t)bh * TT + tt * 64 + sr) * 64 + sc;
    *(int4*)&Vsh[sr][sc]     = *(const int4*)src;
    *(int4*)&Vsh[sr][sc + 8] = *(const int4*)(src + 8);
    __syncthreads();
    const int dr = tid >> 2;
    const int tc = (tid & 3) * 16;
    unsigned short tv[16];
    #pragma unroll
    for (int i = 0; i < 16; i++) {
        int x = tc + i;
        tv[i] = Vsh[16 * (x & 3) + (x >> 2)][dr];
    }
    size_t vo = ((size_t)bh * 64 + dr) * TT + tt * 64 + tc;
    *(int4*)(Vt + vo)     = *(int4*)&tv[0];
    *(int4*)(Vt + vo + 8) = *(int4*)&tv[8];
}

// ---------------- flash attention: barrier-free, K/V fragments direct from global ----------------
// 128-q tile, split-2 over kt, LPT. LDS holds only wave-private Ps.
__global__ __launch_bounds__(256, 4) void flash_k(const unsigned short* __restrict__ Qb,
                                                  const unsigned short* __restrict__ Kb,
                                                  const unsigned short* __restrict__ Vt,
                                                  float* __restrict__ O0, float* __restrict__ O1,
                                                  float* __restrict__ L0, float* __restrict__ L1) {
    __shared__ __align__(16) unsigned short Ps[128][68];
    const int tid  = threadIdx.x;
    const int wave = tid >> 6;
    const int lane = tid & 63;
    const int quad = lane >> 4;
    const int l16  = lane & 15;
    const int qt    = 15 - (blockIdx.x >> 6);   // LPT: longest first
    const int inner = blockIdx.x & 63;
    const int bh    = inner >> 1;
    const int split = inner & 1;
    const int q0 = qt * 128;
    const float SCLOG2 = 0.18033688011112f;  // (1/8) * log2(e)

    // Q fragments from global (k-dim contiguous)
    bf16x8 qf[2][2];
    #pragma unroll
    for (int rb = 0; rb < 2; rb++) {
        int row = q0 + wave * 32 + rb * 16 + l16;
        const unsigned short* qp = Qb + ((size_t)bh * TT + row) * 64 + quad * 8;
        qf[rb][0] = *(const bf16x8*)(qp);
        qf[rb][1] = *(const bf16x8*)(qp + 32);
    }

    floatx4 accO[2][4];
    float lsum[2][4];
    #pragma unroll
    for (int rb = 0; rb < 2; rb++) {
        #pragma unroll
        for (int cb = 0; cb < 4; cb++) accO[rb][cb] = (floatx4){0.f, 0.f, 0.f, 0.f};
        #pragma unroll
        for (int r = 0; r < 4; r++) lsum[rb][r] = 0.f;
    }

    const int kt0 = split * (qt + 1);
    const int kt1 = kt0 + qt + 1;
    const unsigned short* kbase = Kb + (size_t)bh * TT * 64 + l16 * 64 + quad * 8;
    const unsigned short* vbase = Vt + (size_t)bh * 64 * TT + l16 * TT + quad * 8;

    for (int kt = kt0; kt < kt1; kt++) {
        // S = Q K^T — B-fragments straight from global (L2-resident)
        floatx4 sacc[2][4];
        #pragma unroll
        for (int rb = 0; rb < 2; rb++)
            #pragma unroll
            for (int cb = 0; cb < 4; cb++) sacc[rb][cb] = (floatx4){0.f, 0.f, 0.f, 0.f};
        #pragma unroll
        for (int kk = 0; kk < 2; kk++) {
            bf16x8 bk[4];
            #pragma unroll
            for (int cb = 0; cb < 4; cb++)
                bk[cb] = *(const bf16x8*)(kbase + (size_t)(kt * 64 + 16 * cb) * 64 + kk * 32);
            #pragma unroll
            for (int rb = 0; rb < 2; rb++)
                #pragma unroll
                for (int cb = 0; cb < 4; cb++)
                    sacc[rb][cb] = __builtin_amdgcn_mfma_f32_16x16x32_bf16(qf[rb][kk], bk[cb], sacc[rb][cb], 0, 0, 0);
        }

        // p = exp2(s*c); packed write into permuted Ps cols (phys col 4*l16+cb = key 16cb+l16)
        const bool diag = (kt >= 2 * qt);
        #pragma unroll
        for (int rb = 0; rb < 2; rb++) {
            #pragma unroll
            for (int r = 0; r < 4; r++) {
                float p[4];
                #pragma unroll
                for (int cb = 0; cb < 4; cb++) {
                    float pv = __builtin_amdgcn_exp2f(sacc[rb][cb][r] * SCLOG2);
                    if (diag) {
                        int qi = q0 + wave * 32 + rb * 16 + quad * 4 + r;
                        int ki = kt * 64 + cb * 16 + l16;
                        if (ki > qi) pv = 0.f;
                    }
                    lsum[rb][r] += pv;
                    p[cb] = pv;
                }
                unsigned lo = ((__float_as_uint(p[0]) + 0x8000u) >> 16) |
                              ((__float_as_uint(p[1]) + 0x8000u) & 0xffff0000u);
                unsigned hi = ((__float_as_uint(p[2]) + 0x8000u) >> 16) |
                              ((__float_as_uint(p[3]) + 0x8000u) & 0xffff0000u);
                uint2 pk; pk.x = lo; pk.y = hi;
                *(uint2*)&Ps[wave * 32 + rb * 16 + quad * 4 + r][l16 * 4] = pk;
            }
        }

        // O += P V — V fragments from global (key-permuted layout matches Ps)
        #pragma unroll
        for (int kk = 0; kk < 2; kk++) {
            bf16x8 bv[4];
            #pragma unroll
            for (int cb = 0; cb < 4; cb++)
                bv[cb] = *(const bf16x8*)(vbase + (size_t)(16 * cb) * TT + kt * 64 + kk * 32);
            #pragma unroll
            for (int rb = 0; rb < 2; rb++) {
                bf16x8 ap = *(const bf16x8*)&Ps[wave * 32 + rb * 16 + l16][kk * 32 + quad * 8];
                #pragma unroll
                for (int cb = 0; cb < 4; cb++)
                    accO[rb][cb] = __builtin_amdgcn_mfma_f32_16x16x32_bf16(ap, bv[cb], accO[rb][cb], 0, 0, 0);
            }
        }
    }

    // epilogue: store unnormalized partials
    float* Op = split ? O1 : O0;
    float* Lp = split ? L1 : L0;
    #pragma unroll
    for (int rb = 0; rb < 2; rb++) {
        #pragma unroll
        for (int r = 0; r < 4; r++) {
            float l = lsum[rb][r];
            l += __shfl_xor(l, 1);
            l += __shfl_xor(l, 2);
            l += __shfl_xor(l, 4);
            l += __shfl_xor(l, 8);
            int row = q0 + wave * 32 + rb * 16 + quad * 4 + r;
            if (l16 == 0) Lp[(size_t)bh * TT + row] = l;
        }
        #pragma unroll
        for (int cb = 0; cb < 4; cb++)
            #pragma unroll
            for (int r = 0; r < 4; r++) {
                int row = q0 + wave * 32 + rb * 16 + quad * 4 + r;
                Op[((size_t)bh * TT + row) * 64 + 16 * cb + l16] = accO[rb][cb][r];
            }
    }
}

// ---------------- combine: Yb = (O0+O1)/(l0+l1), bf16 [B,T,C] ----------------
__global__ __launch_bounds__(256) void combine_k(const float* __restrict__ O0,
                                                 const float* __restrict__ O1,
                                                 const float* __restrict__ L0,
                                                 const float* __restrict__ L1,
                                                 unsigned short* __restrict__ Yb) {
    int idx = blockIdx.x * 256 + threadIdx.x;   // 0 .. 32*2048*16-1
    int dg  = idx & 15;
    int row = idx >> 4;                          // bh*2048 + t
    float inv = 1.0f / (L0[row] + L1[row]);
    float4 a = ((const float4*)O0)[idx];
    float4 b = ((const float4*)O1)[idx];
    ushort4 o;
    o.x = f2bf((a.x + b.x) * inv);
    o.y = f2bf((a.y + b.y) * inv);
    o.z = f2bf((a.z + b.z) * inv);
    o.w = f2bf((a.w + b.w) * inv);
    int bh = row >> 11, t = row & (TT - 1);
    int bb = bh >> 4, h = bh & 15;
    *(ushort4*)(Yb + ((size_t)(bb * TT + t)) * CC + h * 64 + dg * 4) = o;
}

extern "C" void kernel_launch(void* const* d_in, const int* in_sizes, int n_in,
                              void* d_out, int out_size, void* d_ws, size_t ws_size,
                              hipStream_t stream) {
    (void)in_sizes; (void)n_in; (void)out_size; (void)ws_size;
    const float* x  = (const float*)d_in[0];
    const float* Wq = (const float*)d_in[1];
    const float* Wk = (const float*)d_in[2];
    const float* Wv = (const float*)d_in[3];
    const float* Wo = (const float*)d_in[4];
    float* out = (float*)d_out;
    char* ws = (char*)d_ws;

    unsigned short* xb    = (unsigned short*)(ws + 0);                      //  8 MB
    unsigned short* wqkvb = (unsigned short*)(ws + (8ull  << 20));          //  6 MB
    unsigned short* wob   = (unsigned short*)(ws + (14ull << 20));          //  2 MB
    unsigned short* Qb    = (unsigned short*)(ws + (16ull << 20));          //  8 MB [BH,T,D]
    unsigned short* Kb    = (unsigned short*)(ws + (24ull << 20));          //  8 MB [BH,T,D]
    unsigned short* Vb    = (unsigned short*)(ws + (32ull << 20));          //  8 MB [BH,T,D]
    unsigned short* Vt    = (unsigned short*)(ws + (40ull << 20));          //  8 MB [BH,D,T] key-permuted
    unsigned short* Yb    = (unsigned short*)(ws + (48ull << 20));          //  8 MB
    float* O0 = (float*)(ws + (56ull << 20));                               // 16 MB
    float* O1 = (float*)(ws + (72ull << 20));                               // 16 MB
    float* L0 = (float*)(ws + (88ull << 20));                               // 256 KB
    float* L1 = (float*)(ws + (88ull << 20) + (256ull << 10));              // 256 KB

    cast_all_k<<<8192, 256, 0, stream>>>(x, Wq, Wk, Wv, Wo, xb, wqkvb, wob);
    gemm_qkv_k<<<dim3(24, 32), 256, 0, stream>>>(xb, wqkvb, Qb, Kb, Vb);
    vtr_k<<<dim3(32, 32), 256, 0, stream>>>(Vb, Vt);
    flash_k<<<1024, 256, 0, stream>>>(Qb, Kb, Vt, O0, O1, L0, L1);
    combine_k<<<4096, 256, 0, stream>>>(O0, O1, L0, L1, Yb);
    gemm128_k<<<dim3(8, 32), 256, 0, stream>>>(Yb, wob, out, 4096, 1024, 1024);
}

// Round 5
// 202.248 us; speedup vs baseline: 1.3333x; 1.3333x over previous
//
#include <hip/hip_runtime.h>

// Problem constants
#define BB 2
#define TT 2048
#define CC 1024
#define NH 16
#define HD 64

typedef __attribute__((ext_vector_type(8))) short bf16x8;
typedef __attribute__((ext_vector_type(4))) float floatx4;
typedef __attribute__((ext_vector_type(16))) float floatx16;

__device__ __forceinline__ unsigned short f2bf(float f) {
    union { float f; unsigned int u; } v; v.f = f;
    unsigned int u = v.u;
    u = (u + 0x7fffu + ((u >> 16) & 1u)) >> 16;   // RNE
    return (unsigned short)u;
}

typedef __attribute__((address_space(3))) unsigned char* lds_ptr_t;
typedef const __attribute__((address_space(1))) unsigned char* glob_ptr_t;
__device__ __forceinline__ void gll16(const void* g, void* l) {
    __builtin_amdgcn_global_load_lds((glob_ptr_t)g, (lds_ptr_t)l, 16, 0, 0);
}

// ---------------- fused cast fp32 -> bf16 for x, Wq|Wk|Wv, Wo ----------------
__global__ __launch_bounds__(256) void cast_all_k(const float* __restrict__ x,
                                                  const float* __restrict__ wq,
                                                  const float* __restrict__ wk,
                                                  const float* __restrict__ wv,
                                                  const float* __restrict__ wo,
                                                  unsigned short* __restrict__ xb,
                                                  unsigned short* __restrict__ wqkvb,
                                                  unsigned short* __restrict__ wob) {
    int i = blockIdx.x * 256 + threadIdx.x;   // float4 index, 0..2097151
    const float* src;
    unsigned short* dst;
    if (i < 1048576) {
        src = x + (size_t)i * 4;
        dst = xb + (size_t)i * 4;
    } else {
        int w   = (i - 1048576) >> 18;        // 0..3
        int off = (i - 1048576) & 262143;
        const float* s0 = (w == 0) ? wq : (w == 1) ? wk : (w == 2) ? wv : wo;
        unsigned short* d0 = (w == 3) ? wob : (wqkvb + (size_t)w * 1048576);
        src = s0 + (size_t)off * 4;
        dst = d0 + (size_t)off * 4;
    }
    float4 v = *(const float4*)src;
    ushort4 o;
    o.x = f2bf(v.x); o.y = f2bf(v.y); o.z = f2bf(v.z); o.w = f2bf(v.w);
    *(ushort4*)dst = o;
}

// ---------------- m97-style GEMM: C[M,N] fp32 = A[M,K] * Bt[N,K]^T (out-proj) ----------------
__global__ __launch_bounds__(256) void gemm128_k(const unsigned short* __restrict__ A,
                                                 const unsigned short* __restrict__ Bt,
                                                 float* __restrict__ C, int M, int N, int K) {
    __shared__ __align__(16) unsigned short As[128][32];
    __shared__ __align__(16) unsigned short Bs[128][32];
    const int tid  = threadIdx.x;
    const int wave = tid >> 6;
    const int lane = tid & 63;
    const int quad = lane >> 4;
    const int l16  = lane & 15;
    const int wr = (wave >> 1) * 64;
    const int wc = (wave & 1) * 64;
    const int row0 = blockIdx.y * 128;
    const int col0 = blockIdx.x * 128;
    const int srow = tid >> 2;
    const int scol = (tid & 3) * 8;

    const unsigned short* Ap0 = A  + (size_t)(row0 + srow) * K + scol;
    const unsigned short* Ap1 = A  + (size_t)(row0 + 64 + srow) * K + scol;
    const unsigned short* Bp0 = Bt + (size_t)(col0 + srow) * K + scol;
    const unsigned short* Bp1 = Bt + (size_t)(col0 + 64 + srow) * K + scol;

    floatx4 acc[4][4];
    #pragma unroll
    for (int i = 0; i < 4; i++)
        #pragma unroll
        for (int j = 0; j < 4; j++) acc[i][j] = (floatx4){0.f, 0.f, 0.f, 0.f};

    for (int k0 = 0; k0 < K; k0 += 32) {
        __syncthreads();
        gll16(Ap0 + k0, &As[srow][scol]);
        gll16(Ap1 + k0, &As[64 + srow][scol]);
        gll16(Bp0 + k0, &Bs[srow][scol]);
        gll16(Bp1 + k0, &Bs[64 + srow][scol]);
        __syncthreads();
        bf16x8 af[4], bfr[4];
        #pragma unroll
        for (int i = 0; i < 4; i++) af[i]  = *(const bf16x8*)&As[wr + 16 * i + l16][quad * 8];
        #pragma unroll
        for (int j = 0; j < 4; j++) bfr[j] = *(const bf16x8*)&Bs[wc + 16 * j + l16][quad * 8];
        #pragma unroll
        for (int i = 0; i < 4; i++)
            #pragma unroll
            for (int j = 0; j < 4; j++)
                acc[i][j] = __builtin_amdgcn_mfma_f32_16x16x32_bf16(af[i], bfr[j], acc[i][j], 0, 0, 0);
    }

    #pragma unroll
    for (int i = 0; i < 4; i++)
        #pragma unroll
        for (int j = 0; j < 4; j++)
            #pragma unroll
            for (int r = 0; r < 4; r++) {
                int row = row0 + wr + 16 * i + quad * 4 + r;
                int col = col0 + wc + 16 * j + l16;
                C[(size_t)row * N + col] = acc[i][j][r];
            }
}

// ---------------- QKV GEMM with fused RoPE epilogue (Q pre-scaled by 1/8*log2e) ----------------
__global__ __launch_bounds__(256) void gemm_qkv_k(const unsigned short* __restrict__ A,
                                                  const unsigned short* __restrict__ Bt,
                                                  unsigned short* __restrict__ Qb,
                                                  unsigned short* __restrict__ Kb,
                                                  unsigned short* __restrict__ Vb) {
    __shared__ __align__(16) unsigned short As[128][32];
    __shared__ __align__(16) unsigned short Bs[128][32];
    const int K = 1024;
    const int tid  = threadIdx.x;
    const int wave = tid >> 6;
    const int lane = tid & 63;
    const int quad = lane >> 4;
    const int l16  = lane & 15;
    const int wr = (wave >> 1) * 64;
    const int wc = (wave & 1) * 64;
    const int row0 = blockIdx.y * 128;
    const int col0 = blockIdx.x * 128;
    const int srow = tid >> 2;
    const int scol = (tid & 3) * 8;

    const unsigned short* Ap0 = A  + (size_t)(row0 + srow) * K + scol;
    const unsigned short* Ap1 = A  + (size_t)(row0 + 64 + srow) * K + scol;
    const unsigned short* Bp0 = Bt + (size_t)(col0 + srow) * K + scol;
    const unsigned short* Bp1 = Bt + (size_t)(col0 + 64 + srow) * K + scol;

    floatx4 acc[4][4];
    #pragma unroll
    for (int i = 0; i < 4; i++)
        #pragma unroll
        for (int j = 0; j < 4; j++) acc[i][j] = (floatx4){0.f, 0.f, 0.f, 0.f};

    for (int k0 = 0; k0 < K; k0 += 32) {
        __syncthreads();
        gll16(Ap0 + k0, &As[srow][scol]);
        gll16(Ap1 + k0, &As[64 + srow][scol]);
        gll16(Bp0 + k0, &Bs[srow][scol]);
        gll16(Bp1 + k0, &Bs[64 + srow][scol]);
        __syncthreads();
        bf16x8 af[4], bfr[4];
        #pragma unroll
        for (int i = 0; i < 4; i++) af[i]  = *(const bf16x8*)&As[wr + 16 * i + l16][quad * 8];
        #pragma unroll
        for (int j = 0; j < 4; j++) bfr[j] = *(const bf16x8*)&Bs[wc + 16 * j + l16][quad * 8];
        #pragma unroll
        for (int i = 0; i < 4; i++)
            #pragma unroll
            for (int j = 0; j < 4; j++)
                acc[i][j] = __builtin_amdgcn_mfma_f32_16x16x32_bf16(af[i], bfr[j], acc[i][j], 0, 0, 0);
    }

    const int colw = col0 + wc;           // wave's 64-col stripe base
    const int sect = colw >> 10;          // 0=Q, 1=K, 2=V
    const int h    = (colw & 1023) >> 6;  // head

    if (sect == 2) {
        #pragma unroll
        for (int i = 0; i < 4; i++)
            #pragma unroll
            for (int r = 0; r < 4; r++) {
                int row = row0 + wr + 16 * i + quad * 4 + r;
                int t = row & (TT - 1);
                size_t base = ((size_t)((row >> 11) * NH + h) * TT + t) * 64;
                #pragma unroll
                for (int j = 0; j < 4; j++)
                    Vb[base + 16 * j + l16] = f2bf(acc[i][j][r]);
            }
    } else {
        unsigned short* dst = sect ? Kb : Qb;
        const float qs = sect ? 1.0f : 0.18033688011112f;   // Q pre-scaled by (1/8)*log2(e)
        const float C1 = 0.41524101186092f;        // log2(10000)/32
        const float I2PI = 0.15915494309189535f;
        float invf0 = __builtin_amdgcn_exp2f(-(float)l16 * C1) * I2PI;
        float invf1 = __builtin_amdgcn_exp2f(-(float)(16 + l16) * C1) * I2PI;
        #pragma unroll
        for (int i = 0; i < 4; i++) {
            #pragma unroll
            for (int r = 0; r < 4; r++) {
                int row = row0 + wr + 16 * i + quad * 4 + r;
                int t = row & (TT - 1);
                size_t base = ((size_t)((row >> 11) * NH + h) * TT + t) * 64;
                #pragma unroll
                for (int jj = 0; jj < 2; jj++) {
                    float rev = (float)t * (jj ? invf1 : invf0);
                    rev -= floorf(rev);
                    float ang = rev * 6.2831853071796f;
                    float c = __cosf(ang), s = __sinf(ang);
                    float v1 = acc[i][jj][r], v2 = acc[i][jj + 2][r];
                    dst[base + 16 * jj + l16]      = f2bf((v1 * c - v2 * s) * qs);
                    dst[base + 16 * jj + 32 + l16] = f2bf((v2 * c + v1 * s) * qs);
                }
            }
        }
    }
}

// ---------------- V transpose: Vb [BH,T,D] -> Vt [BH,D,T], key slot-permuted ----------------
// slot s within each 64-key tile holds key (s & ~15) + sigma(s&15),
// sigma(x) = (x&3) + 8*((x>>2)&1) + 4*((x>>3)&1)  (matches 32x32 MFMA A/B k-slot order)
__global__ __launch_bounds__(256) void vtr_k(const unsigned short* __restrict__ Vb,
                                             unsigned short* __restrict__ Vt) {
    __shared__ __align__(16) unsigned short Vsh[64][70];
    const int tid = threadIdx.x;
    const int tt = blockIdx.x;    // t-tile 0..31
    const int bh = blockIdx.y;    // 0..31
    const int sr = tid >> 2;
    const int sc = (tid & 3) * 16;
    const unsigned short* src = Vb + ((size_t)bh * TT + tt * 64 + sr) * 64 + sc;
    *(int4*)&Vsh[sr][sc]     = *(const int4*)src;
    *(int4*)&Vsh[sr][sc + 8] = *(const int4*)(src + 8);
    __syncthreads();
    const int dr = tid >> 2;
    const int tc = (tid & 3) * 16;
    unsigned short tv[16];
    #pragma unroll
    for (int i = 0; i < 16; i++) {
        int x = tc + i;
        int key = (x & ~15) + (x & 3) + ((x >> 2) & 1) * 8 + ((x >> 3) & 1) * 4;
        tv[i] = Vsh[key][dr];
    }
    size_t vo = ((size_t)bh * 64 + dr) * TT + tt * 64 + tc;
    *(int4*)(Vt + vo)     = *(int4*)&tv[0];
    *(int4*)(Vt + vo + 8) = *(int4*)&tv[8];
}

// ---------------- flash attention: S^T = K Q^T via 32x32x16 MFMA, P stays in registers ----------------
// 128-q tile (4 waves x 32 q), split-2 over kt, LPT. LDS holds only K/V tiles.
__global__ __launch_bounds__(256, 4) void flash_k(const unsigned short* __restrict__ Qb,
                                                  const unsigned short* __restrict__ Kb,
                                                  const unsigned short* __restrict__ Vt,
                                                  float* __restrict__ O0, float* __restrict__ O1,
                                                  float* __restrict__ L0, float* __restrict__ L1) {
    __shared__ __align__(16) unsigned short Ks[64][72];   // [key][d]
    __shared__ __align__(16) unsigned short Vs[64][72];   // [d][key-slot] (sigma-permuted)
    const int tid  = threadIdx.x;
    const int wave = tid >> 6;
    const int lane = tid & 63;
    const int h    = lane >> 5;          // half-wave
    const int l32  = lane & 31;
    const int qt    = 15 - (blockIdx.x >> 6);   // LPT: longest first
    const int inner = blockIdx.x & 63;
    const int bh    = inner >> 1;
    const int split = inner & 1;
    const int q0 = qt * 128;
    const int qw = q0 + wave * 32 + l32;        // this lane's query row
    const int sr = tid >> 2;
    const int sc = (tid & 3) * 16;

    // Q as B-operand fragments: B[n=q=l32][k-slot h*8+j] over 4 k-steps of d
    bf16x8 qf[4];
    {
        const unsigned short* qp = Qb + ((size_t)bh * TT + qw) * 64 + h * 8;
        #pragma unroll
        for (int kk = 0; kk < 4; kk++) qf[kk] = *(const bf16x8*)(qp + kk * 16);
    }

    floatx16 accO[2];
    accO[0] = (floatx16)(0.f);
    accO[1] = (floatx16)(0.f);
    float lsum = 0.f;

    const int kt0 = split * (qt + 1);
    const int kt1 = kt0 + qt + 1;
    const unsigned short* kbase = Kb + (size_t)bh * TT * 64;
    const unsigned short* vbase = Vt + (size_t)bh * 64 * TT;

    // prefetch first tile into registers
    const unsigned short* kp = kbase + ((size_t)(kt0 * 64) + sr) * 64 + sc;
    const unsigned short* vp = vbase + (size_t)sr * TT + kt0 * 64 + sc;
    int4 ka = *(const int4*)kp, kb2 = *(const int4*)(kp + 8);
    int4 va = *(const int4*)vp, vb2 = *(const int4*)(vp + 8);

    for (int kt = kt0; kt < kt1; kt++) {
        __syncthreads();
        *(int4*)&Ks[sr][sc]     = ka;
        *(int4*)&Ks[sr][sc + 8] = kb2;
        *(int4*)&Vs[sr][sc]     = va;
        *(int4*)&Vs[sr][sc + 8] = vb2;
        __syncthreads();
        if (kt + 1 < kt1) {
            const unsigned short* kp2 = kbase + ((size_t)((kt + 1) * 64) + sr) * 64 + sc;
            const unsigned short* vp2 = vbase + (size_t)sr * TT + (kt + 1) * 64 + sc;
            ka  = *(const int4*)kp2; kb2 = *(const int4*)(kp2 + 8);
            va  = *(const int4*)vp2; vb2 = *(const int4*)(vp2 + 8);
        }

        const bool diag = (kt >= 2 * qt);
        bf16x8 pfrag[4];    // P^T B-fragments for PV, k-slots in sigma order

        #pragma unroll
        for (int mb = 0; mb < 2; mb++) {
            // S^T tile [32 keys][32 q]: A = K rows, B = Q
            floatx16 sacc = (floatx16)(0.f);
            #pragma unroll
            for (int kk = 0; kk < 4; kk++) {
                bf16x8 kf = *(const bf16x8*)&Ks[32 * mb + l32][kk * 16 + h * 8];
                sacc = __builtin_amdgcn_mfma_f32_32x32x16_bf16(kf, qf[kk], sacc, 0, 0, 0);
            }
            // softmax: p = exp2(s) (scale folded into Q), per-lane lsum (col = q fixed)
            float p[16];
            const int kmb = kt * 64 + 32 * mb + 4 * h;
            #pragma unroll
            for (int r = 0; r < 16; r++) {
                float pv = __builtin_amdgcn_exp2f(sacc[r]);
                if (diag) {
                    int ki = kmb + (r & 3) + 8 * (r >> 2);
                    if (ki > qw) pv = 0.f;
                }
                lsum += pv;
                p[r] = pv;
            }
            // pack into PV B-frags: identity reg mapping (keys sigma-permuted in Vs)
            #pragma unroll
            for (int half = 0; half < 2; half++) {
                union { bf16x8 v; unsigned u[4]; } pk;
                #pragma unroll
                for (int i = 0; i < 4; i++) {
                    unsigned ulo = __float_as_uint(p[half * 8 + 2 * i]);
                    unsigned uhi = __float_as_uint(p[half * 8 + 2 * i + 1]);
                    pk.u[i] = (ulo >> 16) | (uhi & 0xffff0000u);
                }
                pfrag[2 * mb + half] = pk.v;
            }
        }

        // O^T += V^T P^T : A = Vs rows (d), B = pfrag
        #pragma unroll
        for (int mbo = 0; mbo < 2; mbo++) {
            #pragma unroll
            for (int kk = 0; kk < 4; kk++) {
                bf16x8 vf = *(const bf16x8*)&Vs[32 * mbo + l32][kk * 16 + h * 8];
                accO[mbo] = __builtin_amdgcn_mfma_f32_32x32x16_bf16(vf, pfrag[kk], accO[mbo], 0, 0, 0);
            }
        }
    }

    // epilogue: lsum across half-waves (lanes l, l+32 share q), store unnormalized partials
    lsum += __shfl_xor(lsum, 32);
    float* Op = split ? O1 : O0;
    float* Lp = split ? L1 : L0;
    if (lane < 32) Lp[(size_t)bh * TT + qw] = lsum;
    float* orow = Op + ((size_t)bh * TT + qw) * 64;
    #pragma unroll
    for (int mbo = 0; mbo < 2; mbo++)
        #pragma unroll
        for (int a = 0; a < 4; a++) {
            float4 o4;
            o4.x = accO[mbo][4 * a + 0];
            o4.y = accO[mbo][4 * a + 1];
            o4.z = accO[mbo][4 * a + 2];
            o4.w = accO[mbo][4 * a + 3];
            *(float4*)(orow + 32 * mbo + 8 * a + 4 * h) = o4;
        }
}

// ---------------- combine: Yb = (O0+O1)/(l0+l1), bf16 [B,T,C] ----------------
__global__ __launch_bounds__(256) void combine_k(const float* __restrict__ O0,
                                                 const float* __restrict__ O1,
                                                 const float* __restrict__ L0,
                                                 const float* __restrict__ L1,
                                                 unsigned short* __restrict__ Yb) {
    int idx = blockIdx.x * 256 + threadIdx.x;   // 0 .. 32*2048*16-1
    int dg  = idx & 15;
    int row = idx >> 4;                          // bh*2048 + t
    float inv = 1.0f / (L0[row] + L1[row]);
    float4 a = ((const float4*)O0)[idx];
    float4 b = ((const float4*)O1)[idx];
    ushort4 o;
    o.x = f2bf((a.x + b.x) * inv);
    o.y = f2bf((a.y + b.y) * inv);
    o.z = f2bf((a.z + b.z) * inv);
    o.w = f2bf((a.w + b.w) * inv);
    int bh = row >> 11, t = row & (TT - 1);
    int bb = bh >> 4, h = bh & 15;
    *(ushort4*)(Yb + ((size_t)(bb * TT + t)) * CC + h * 64 + dg * 4) = o;
}

extern "C" void kernel_launch(void* const* d_in, const int* in_sizes, int n_in,
                              void* d_out, int out_size, void* d_ws, size_t ws_size,
                              hipStream_t stream) {
    (void)in_sizes; (void)n_in; (void)out_size; (void)ws_size;
    const float* x  = (const float*)d_in[0];
    const float* Wq = (const float*)d_in[1];
    const float* Wk = (const float*)d_in[2];
    const float* Wv = (const float*)d_in[3];
    const float* Wo = (const float*)d_in[4];
    float* out = (float*)d_out;
    char* ws = (char*)d_ws;

    unsigned short* xb    = (unsigned short*)(ws + 0);                      //  8 MB
    unsigned short* wqkvb = (unsigned short*)(ws + (8ull  << 20));          //  6 MB
    unsigned short* wob   = (unsigned short*)(ws + (14ull << 20));          //  2 MB
    unsigned short* Qb    = (unsigned short*)(ws + (16ull << 20));          //  8 MB [BH,T,D] (pre-scaled)
    unsigned short* Kb    = (unsigned short*)(ws + (24ull << 20));          //  8 MB [BH,T,D]
    unsigned short* Vb    = (unsigned short*)(ws + (32ull << 20));          //  8 MB [BH,T,D]
    unsigned short* Vt    = (unsigned short*)(ws + (40ull << 20));          //  8 MB [BH,D,T] slot-permuted
    unsigned short* Yb    = (unsigned short*)(ws + (48ull << 20));          //  8 MB
    float* O0 = (float*)(ws + (56ull << 20));                               // 16 MB
    float* O1 = (float*)(ws + (72ull << 20));                               // 16 MB
    float* L0 = (float*)(ws + (88ull << 20));                               // 256 KB
    float* L1 = (float*)(ws + (88ull << 20) + (256ull << 10));              // 256 KB

    cast_all_k<<<8192, 256, 0, stream>>>(x, Wq, Wk, Wv, Wo, xb, wqkvb, wob);
    gemm_qkv_k<<<dim3(24, 32), 256, 0, stream>>>(xb, wqkvb, Qb, Kb, Vb);
    vtr_k<<<dim3(32, 32), 256, 0, stream>>>(Vb, Vt);
    flash_k<<<1024, 256, 0, stream>>>(Qb, Kb, Vt, O0, O1, L0, L1);
    combine_k<<<4096, 256, 0, stream>>>(O0, O1, L0, L1, Yb);
    gemm128_k<<<dim3(8, 32), 256, 0, stream>>>(Yb, wob, out, 4096, 1024, 1024);
}

// Round 6
// 192.007 us; speedup vs baseline: 1.4044x; 1.0533x over previous
//
#include <hip/hip_runtime.h>

// Problem constants
#define BB 2
#define TT 2048
#define CC 1024
#define NH 16
#define HD 64

typedef __attribute__((ext_vector_type(8))) short bf16x8;
typedef __attribute__((ext_vector_type(4))) float floatx4;
typedef __attribute__((ext_vector_type(16))) float floatx16;

__device__ __forceinline__ unsigned short f2bf(float f) {
    union { float f; unsigned int u; } v; v.f = f;
    unsigned int u = v.u;
    u = (u + 0x7fffu + ((u >> 16) & 1u)) >> 16;   // RNE
    return (unsigned short)u;
}
__device__ __forceinline__ float bf2f(unsigned short u) {
    return __uint_as_float((unsigned)u << 16);
}

typedef __attribute__((address_space(3))) unsigned char* lds_ptr_t;
typedef const __attribute__((address_space(1))) unsigned char* glob_ptr_t;
__device__ __forceinline__ void gll16(const void* g, void* l) {
    __builtin_amdgcn_global_load_lds((glob_ptr_t)g, (lds_ptr_t)l, 16, 0, 0);
}

// ---------------- fused cast fp32 -> bf16 + RoPE table build ----------------
__global__ __launch_bounds__(256) void cast_all_k(const float* __restrict__ x,
                                                  const float* __restrict__ wq,
                                                  const float* __restrict__ wk,
                                                  const float* __restrict__ wv,
                                                  const float* __restrict__ wo,
                                                  unsigned short* __restrict__ xb,
                                                  unsigned short* __restrict__ wqkvb,
                                                  unsigned short* __restrict__ wob,
                                                  float2* __restrict__ tabQ,
                                                  float2* __restrict__ tabK) {
    if (blockIdx.x >= 8192) {   // RoPE tables: 2048 t x 32 pairs
        int idx = (blockIdx.x - 8192) * 256 + threadIdx.x;   // 0..65535
        int t = idx >> 5, j = idx & 31;
        const float C1 = 0.41524101186092f;        // log2(10000)/32
        const float I2PI = 0.15915494309189535f;
        float rev = (float)t * (__builtin_amdgcn_exp2f(-(float)j * C1) * I2PI);
        rev -= floorf(rev);
        float ang = rev * 6.2831853071796f;
        float c = __cosf(ang), s = __sinf(ang);
        const float qs = 0.18033688011112f;        // (1/8)*log2(e), folded into Q table
        tabK[idx] = make_float2(c, s);
        tabQ[idx] = make_float2(c * qs, s * qs);
        return;
    }
    int i = blockIdx.x * 256 + threadIdx.x;   // float4 index
    const float* src;
    unsigned short* dst;
    if (i < 1048576) {
        src = x + (size_t)i * 4;
        dst = xb + (size_t)i * 4;
    } else {
        int w   = (i - 1048576) >> 18;        // 0..3
        int off = (i - 1048576) & 262143;
        const float* s0 = (w == 0) ? wq : (w == 1) ? wk : (w == 2) ? wv : wo;
        unsigned short* d0 = (w == 3) ? wob : (wqkvb + (size_t)w * 1048576);
        src = s0 + (size_t)off * 4;
        dst = d0 + (size_t)off * 4;
    }
    float4 v = *(const float4*)src;
    ushort4 o;
    o.x = f2bf(v.x); o.y = f2bf(v.y); o.z = f2bf(v.z); o.w = f2bf(v.w);
    *(ushort4*)dst = o;
}

// ---------------- out-proj GEMM: C[M,N] fp32 = A[M,K] * Bt[N,K]^T, XCD-swizzled 1-D grid ----------------
__global__ __launch_bounds__(256) void gemm128_k(const unsigned short* __restrict__ A,
                                                 const unsigned short* __restrict__ Bt,
                                                 float* __restrict__ C, int N, int K) {
    __shared__ __align__(16) unsigned short As[128][32];
    __shared__ __align__(16) unsigned short Bs[128][32];
    const int tid  = threadIdx.x;
    const int wave = tid >> 6;
    const int lane = tid & 63;
    const int quad = lane >> 4;
    const int l16  = lane & 15;
    const int wr = (wave >> 1) * 64;
    const int wc = (wave & 1) * 64;
    // XCD swizzle: 256 blocks, xcd gets 4 consecutive row-tiles
    const int bid = blockIdx.x;
    const int xcd = bid & 7, sl = bid >> 3;          // sl 0..31
    const int row0 = (xcd * 4 + (sl >> 3)) * 128;
    const int col0 = (sl & 7) * 128;
    const int srow = tid >> 2;
    const int scol = (tid & 3) * 8;

    const unsigned short* Ap0 = A  + (size_t)(row0 + srow) * K + scol;
    const unsigned short* Ap1 = A  + (size_t)(row0 + 64 + srow) * K + scol;
    const unsigned short* Bp0 = Bt + (size_t)(col0 + srow) * K + scol;
    const unsigned short* Bp1 = Bt + (size_t)(col0 + 64 + srow) * K + scol;

    floatx4 acc[4][4];
    #pragma unroll
    for (int i = 0; i < 4; i++)
        #pragma unroll
        for (int j = 0; j < 4; j++) acc[i][j] = (floatx4){0.f, 0.f, 0.f, 0.f};

    for (int k0 = 0; k0 < K; k0 += 32) {
        __syncthreads();
        gll16(Ap0 + k0, &As[srow][scol]);
        gll16(Ap1 + k0, &As[64 + srow][scol]);
        gll16(Bp0 + k0, &Bs[srow][scol]);
        gll16(Bp1 + k0, &Bs[64 + srow][scol]);
        __syncthreads();
        bf16x8 af[4], bfr[4];
        #pragma unroll
        for (int i = 0; i < 4; i++) af[i]  = *(const bf16x8*)&As[wr + 16 * i + l16][quad * 8];
        #pragma unroll
        for (int j = 0; j < 4; j++) bfr[j] = *(const bf16x8*)&Bs[wc + 16 * j + l16][quad * 8];
        #pragma unroll
        for (int i = 0; i < 4; i++)
            #pragma unroll
            for (int j = 0; j < 4; j++)
                acc[i][j] = __builtin_amdgcn_mfma_f32_16x16x32_bf16(af[i], bfr[j], acc[i][j], 0, 0, 0);
    }

    #pragma unroll
    for (int i = 0; i < 4; i++)
        #pragma unroll
        for (int j = 0; j < 4; j++)
            #pragma unroll
            for (int r = 0; r < 4; r++) {
                int row = row0 + wr + 16 * i + quad * 4 + r;
                int col = col0 + wc + 16 * j + l16;
                C[(size_t)row * N + col] = acc[i][j][r];
            }
}

// ---------------- QKV GEMM, table-RoPE + LDS-bounce coalesced epilogue ----------------
// A = x bf16 [4096,1024], Bt = Wq|Wk|Wv bf16 [3072,1024]. 1-D grid 768, XCD-swizzled.
__global__ __launch_bounds__(256) void gemm_qkv_k(const unsigned short* __restrict__ A,
                                                  const unsigned short* __restrict__ Bt,
                                                  const float2* __restrict__ tabQ,
                                                  const float2* __restrict__ tabK,
                                                  unsigned short* __restrict__ Qb,
                                                  unsigned short* __restrict__ Kb,
                                                  unsigned short* __restrict__ Vb) {
    __shared__ __align__(16) unsigned short SMEM[128 * 128];   // 32 KB: As+Bs during loop, Eb in epilogue
    unsigned short (*As)[32] = (unsigned short(*)[32])SMEM;
    unsigned short (*Bs)[32] = (unsigned short(*)[32])(SMEM + 128 * 32);
    unsigned short (*Eb)[128] = (unsigned short(*)[128])SMEM;
    const int K = 1024;
    const int tid  = threadIdx.x;
    const int wave = tid >> 6;
    const int lane = tid & 63;
    const int quad = lane >> 4;
    const int l16  = lane & 15;
    const int wr = (wave >> 1) * 64;
    const int wc = (wave & 1) * 64;
    // XCD swizzle: 768 blocks; xcd x owns row-tiles 4x..4x+3 (A stays in its L2)
    const int bid = blockIdx.x;
    const int xcd = bid & 7, sl = bid >> 3;          // sl 0..95
    const int row0 = (xcd * 4 + sl / 24) * 128;
    const int col0 = (sl % 24) * 128;
    const int srow = tid >> 2;
    const int scol = (tid & 3) * 8;

    const unsigned short* Ap0 = A  + (size_t)(row0 + srow) * K + scol;
    const unsigned short* Ap1 = A  + (size_t)(row0 + 64 + srow) * K + scol;
    const unsigned short* Bp0 = Bt + (size_t)(col0 + srow) * K + scol;
    const unsigned short* Bp1 = Bt + (size_t)(col0 + 64 + srow) * K + scol;

    floatx4 acc[4][4];
    #pragma unroll
    for (int i = 0; i < 4; i++)
        #pragma unroll
        for (int j = 0; j < 4; j++) acc[i][j] = (floatx4){0.f, 0.f, 0.f, 0.f};

    for (int k0 = 0; k0 < K; k0 += 32) {
        __syncthreads();
        gll16(Ap0 + k0, &As[srow][scol]);
        gll16(Ap1 + k0, &As[64 + srow][scol]);
        gll16(Bp0 + k0, &Bs[srow][scol]);
        gll16(Bp1 + k0, &Bs[64 + srow][scol]);
        __syncthreads();
        bf16x8 af[4], bfr[4];
        #pragma unroll
        for (int i = 0; i < 4; i++) af[i]  = *(const bf16x8*)&As[wr + 16 * i + l16][quad * 8];
        #pragma unroll
        for (int j = 0; j < 4; j++) bfr[j] = *(const bf16x8*)&Bs[wc + 16 * j + l16][quad * 8];
        #pragma unroll
        for (int i = 0; i < 4; i++)
            #pragma unroll
            for (int j = 0; j < 4; j++)
                acc[i][j] = __builtin_amdgcn_mfma_f32_16x16x32_bf16(af[i], bfr[j], acc[i][j], 0, 0, 0);
    }

    // ---- Phase 1: acc -> Eb (bf16), XOR-granule swizzle (granule = 8 shorts, phys g = g ^ (row&15)) ----
    __syncthreads();   // all waves done reading As/Bs
    #pragma unroll
    for (int i = 0; i < 4; i++)
        #pragma unroll
        for (int j = 0; j < 4; j++)
            #pragma unroll
            for (int r = 0; r < 4; r++) {
                int erow = wr + 16 * i + quad * 4 + r;
                int col  = wc + 16 * j + l16;
                int pcol = (((col >> 3) ^ (erow & 15)) << 3) | (col & 7);
                Eb[erow][pcol] = f2bf(acc[i][j][r]);
            }
    __syncthreads();

    // ---- Phase 2: row-wise readback, RoPE via table, coalesced stores ----
    const int row  = tid >> 1;            // 0..127
    const int half = tid & 1;
    const int grow = row0 + row;
    const int t    = grow & (TT - 1);
    const int bb   = grow >> 11;
    const int sect = col0 >> 10;                        // 0=Q,1=K,2=V
    const int hh   = ((col0 & 1023) >> 6) + half;       // head
    union { int4 q[8]; unsigned short u[64]; } raw;
    #pragma unroll
    for (int i = 0; i < 8; i++) {
        int pg = (half * 8 + i) ^ (row & 15);
        raw.q[i] = *(const int4*)&Eb[row][pg << 3];
    }
    size_t obase = ((size_t)(bb * NH + hh) * TT + t) * 64;
    if (sect == 2) {
        #pragma unroll
        for (int i = 0; i < 8; i++) *(int4*)(Vb + obase + 8 * i) = raw.q[i];
    } else {
        const float4* tab = (const float4*)((sect ? tabK : tabQ) + (size_t)t * 32);
        unsigned short* dst = sect ? Kb : Qb;
        union { int4 q[8]; unsigned short u[64]; } o;
        #pragma unroll
        for (int i = 0; i < 16; i++) {
            float4 cs = tab[i];      // {c0,s0,c1,s1} for pairs j=2i, 2i+1
            int j0 = 2 * i, j1 = 2 * i + 1;
            float a0 = bf2f(raw.u[j0]), b0 = bf2f(raw.u[j0 + 32]);
            float a1 = bf2f(raw.u[j1]), b1 = bf2f(raw.u[j1 + 32]);
            o.u[j0]      = f2bf(a0 * cs.x - b0 * cs.y);
            o.u[j0 + 32] = f2bf(b0 * cs.x + a0 * cs.y);
            o.u[j1]      = f2bf(a1 * cs.z - b1 * cs.w);
            o.u[j1 + 32] = f2bf(b1 * cs.z + a1 * cs.w);
        }
        #pragma unroll
        for (int i = 0; i < 8; i++) *(int4*)(dst + obase + 8 * i) = o.q[i];
    }
}

// ---------------- V transpose: Vb [BH,T,D] -> Vt [BH,D,T], key slot-permuted ----------------
__global__ __launch_bounds__(256) void vtr_k(const unsigned short* __restrict__ Vb,
                                             unsigned short* __restrict__ Vt) {
    __shared__ __align__(16) unsigned short Vsh[64][70];
    const int tid = threadIdx.x;
    const int tt = blockIdx.x;    // t-tile 0..31
    const int bh = blockIdx.y;    // 0..31
    const int sr = tid >> 2;
    const int sc = (tid & 3) * 16;
    const unsigned short* src = Vb + ((size_t)bh * TT + tt * 64 + sr) * 64 + sc;
    *(int4*)&Vsh[sr][sc]     = *(const int4*)src;
    *(int4*)&Vsh[sr][sc + 8] = *(const int4*)(src + 8);
    __syncthreads();
    const int dr = tid >> 2;
    const int tc = (tid & 3) * 16;
    unsigned short tv[16];
    #pragma unroll
    for (int i = 0; i < 16; i++) {
        int x = tc + i;
        int key = (x & ~15) + (x & 3) + ((x >> 2) & 1) * 8 + ((x >> 3) & 1) * 4;
        tv[i] = Vsh[key][dr];
    }
    size_t vo = ((size_t)bh * 64 + dr) * TT + tt * 64 + tc;
    *(int4*)(Vt + vo)     = *(int4*)&tv[0];
    *(int4*)(Vt + vo + 8) = *(int4*)&tv[8];
}

// ---------------- flash attention: S^T = K Q^T via 32x32x16 MFMA, P in registers, bf16 partials ----------------
__global__ __launch_bounds__(256, 4) void flash_k(const unsigned short* __restrict__ Qb,
                                                  const unsigned short* __restrict__ Kb,
                                                  const unsigned short* __restrict__ Vt,
                                                  unsigned short* __restrict__ O0,
                                                  unsigned short* __restrict__ O1,
                                                  float* __restrict__ L0, float* __restrict__ L1) {
    __shared__ __align__(16) unsigned short Ks[64][72];   // [key][d]
    __shared__ __align__(16) unsigned short Vs[64][72];   // [d][key-slot] (sigma-permuted)
    const int tid  = threadIdx.x;
    const int wave = tid >> 6;
    const int lane = tid & 63;
    const int h    = lane >> 5;
    const int l32  = lane & 31;
    const int qt    = 15 - (blockIdx.x >> 6);   // LPT
    const int inner = blockIdx.x & 63;
    const int bh    = inner >> 1;
    const int split = inner & 1;
    const int q0 = qt * 128;
    const int qw = q0 + wave * 32 + l32;
    const int sr = tid >> 2;
    const int sc = (tid & 3) * 16;

    bf16x8 qf[4];
    {
        const unsigned short* qp = Qb + ((size_t)bh * TT + qw) * 64 + h * 8;
        #pragma unroll
        for (int kk = 0; kk < 4; kk++) qf[kk] = *(const bf16x8*)(qp + kk * 16);
    }

    floatx16 accO[2];
    accO[0] = (floatx16)(0.f);
    accO[1] = (floatx16)(0.f);
    float lsum = 0.f;

    const int kt0 = split * (qt + 1);
    const int kt1 = kt0 + qt + 1;
    const unsigned short* kbase = Kb + (size_t)bh * TT * 64;
    const unsigned short* vbase = Vt + (size_t)bh * 64 * TT;

    const unsigned short* kp = kbase + ((size_t)(kt0 * 64) + sr) * 64 + sc;
    const unsigned short* vp = vbase + (size_t)sr * TT + kt0 * 64 + sc;
    int4 ka = *(const int4*)kp, kb2 = *(const int4*)(kp + 8);
    int4 va = *(const int4*)vp, vb2 = *(const int4*)(vp + 8);

    for (int kt = kt0; kt < kt1; kt++) {
        __syncthreads();
        *(int4*)&Ks[sr][sc]     = ka;
        *(int4*)&Ks[sr][sc + 8] = kb2;
        *(int4*)&Vs[sr][sc]     = va;
        *(int4*)&Vs[sr][sc + 8] = vb2;
        __syncthreads();
        if (kt + 1 < kt1) {
            const unsigned short* kp2 = kbase + ((size_t)((kt + 1) * 64) + sr) * 64 + sc;
            const unsigned short* vp2 = vbase + (size_t)sr * TT + (kt + 1) * 64 + sc;
            ka  = *(const int4*)kp2; kb2 = *(const int4*)(kp2 + 8);
            va  = *(const int4*)vp2; vb2 = *(const int4*)(vp2 + 8);
        }

        const bool diag = (kt >= 2 * qt);
        bf16x8 pfrag[4];

        #pragma unroll
        for (int mb = 0; mb < 2; mb++) {
            floatx16 sacc = (floatx16)(0.f);
            #pragma unroll
            for (int kk = 0; kk < 4; kk++) {
                bf16x8 kf = *(const bf16x8*)&Ks[32 * mb + l32][kk * 16 + h * 8];
                sacc = __builtin_amdgcn_mfma_f32_32x32x16_bf16(kf, qf[kk], sacc, 0, 0, 0);
            }
            float p[16];
            const int kmb = kt * 64 + 32 * mb + 4 * h;
            #pragma unroll
            for (int r = 0; r < 16; r++) {
                float pv = __builtin_amdgcn_exp2f(sacc[r]);
                if (diag) {
                    int ki = kmb + (r & 3) + 8 * (r >> 2);
                    if (ki > qw) pv = 0.f;
                }
                lsum += pv;
                p[r] = pv;
            }
            #pragma unroll
            for (int half = 0; half < 2; half++) {
                union { bf16x8 v; unsigned u[4]; } pk;
                #pragma unroll
                for (int i = 0; i < 4; i++) {
                    unsigned ulo = __float_as_uint(p[half * 8 + 2 * i]);
                    unsigned uhi = __float_as_uint(p[half * 8 + 2 * i + 1]);
                    pk.u[i] = (ulo >> 16) | (uhi & 0xffff0000u);
                }
                pfrag[2 * mb + half] = pk.v;
            }
        }

        #pragma unroll
        for (int mbo = 0; mbo < 2; mbo++) {
            #pragma unroll
            for (int kk = 0; kk < 4; kk++) {
                bf16x8 vf = *(const bf16x8*)&Vs[32 * mbo + l32][kk * 16 + h * 8];
                accO[mbo] = __builtin_amdgcn_mfma_f32_32x32x16_bf16(vf, pfrag[kk], accO[mbo], 0, 0, 0);
            }
        }
    }

    // epilogue: bf16 unnormalized partials
    lsum += __shfl_xor(lsum, 32);
    unsigned short* Op = split ? O1 : O0;
    float* Lp = split ? L1 : L0;
    if (lane < 32) Lp[(size_t)bh * TT + qw] = lsum;
    unsigned short* orow = Op + ((size_t)bh * TT + qw) * 64;
    #pragma unroll
    for (int mbo = 0; mbo < 2; mbo++)
        #pragma unroll
        for (int a = 0; a < 4; a++) {
            ushort4 o4;
            o4.x = f2bf(accO[mbo][4 * a + 0]);
            o4.y = f2bf(accO[mbo][4 * a + 1]);
            o4.z = f2bf(accO[mbo][4 * a + 2]);
            o4.w = f2bf(accO[mbo][4 * a + 3]);
            *(ushort4*)(orow + 32 * mbo + 8 * a + 4 * h) = o4;
        }
}

// ---------------- combine: Yb = (O0+O1)/(l0+l1), bf16 [B,T,C] ----------------
__global__ __launch_bounds__(256) void combine_k(const unsigned short* __restrict__ O0,
                                                 const unsigned short* __restrict__ O1,
                                                 const float* __restrict__ L0,
                                                 const float* __restrict__ L1,
                                                 unsigned short* __restrict__ Yb) {
    int idx = blockIdx.x * 256 + threadIdx.x;   // ushort4 index, 0..1048575
    int dg  = idx & 15;
    int row = idx >> 4;                          // bh*2048 + t
    float inv = 1.0f / (L0[row] + L1[row]);
    uint2 a = ((const uint2*)O0)[idx];
    uint2 b = ((const uint2*)O1)[idx];
    float a0 = __uint_as_float(a.x << 16),      b0 = __uint_as_float(b.x << 16);
    float a1 = __uint_as_float(a.x & 0xffff0000u), b1 = __uint_as_float(b.x & 0xffff0000u);
    float a2 = __uint_as_float(a.y << 16),      b2 = __uint_as_float(b.y << 16);
    float a3 = __uint_as_float(a.y & 0xffff0000u), b3 = __uint_as_float(b.y & 0xffff0000u);
    ushort4 o;
    o.x = f2bf((a0 + b0) * inv);
    o.y = f2bf((a1 + b1) * inv);
    o.z = f2bf((a2 + b2) * inv);
    o.w = f2bf((a3 + b3) * inv);
    int bh = row >> 11, t = row & (TT - 1);
    int bb = bh >> 4, hh = bh & 15;
    *(ushort4*)(Yb + ((size_t)(bb * TT + t)) * CC + hh * 64 + dg * 4) = o;
}

extern "C" void kernel_launch(void* const* d_in, const int* in_sizes, int n_in,
                              void* d_out, int out_size, void* d_ws, size_t ws_size,
                              hipStream_t stream) {
    (void)in_sizes; (void)n_in; (void)out_size; (void)ws_size;
    const float* x  = (const float*)d_in[0];
    const float* Wq = (const float*)d_in[1];
    const float* Wk = (const float*)d_in[2];
    const float* Wv = (const float*)d_in[3];
    const float* Wo = (const float*)d_in[4];
    float* out = (float*)d_out;
    char* ws = (char*)d_ws;

    unsigned short* xb    = (unsigned short*)(ws + 0);                      //  8 MB
    unsigned short* wqkvb = (unsigned short*)(ws + (8ull  << 20));          //  6 MB
    unsigned short* wob   = (unsigned short*)(ws + (14ull << 20));          //  2 MB
    unsigned short* Qb    = (unsigned short*)(ws + (16ull << 20));          //  8 MB [BH,T,D] (pre-scaled)
    unsigned short* Kb    = (unsigned short*)(ws + (24ull << 20));          //  8 MB [BH,T,D]
    unsigned short* Vb    = (unsigned short*)(ws + (32ull << 20));          //  8 MB [BH,T,D]
    unsigned short* Vt    = (unsigned short*)(ws + (40ull << 20));          //  8 MB [BH,D,T] slot-permuted
    unsigned short* Yb    = (unsigned short*)(ws + (48ull << 20));          //  8 MB
    unsigned short* O0    = (unsigned short*)(ws + (56ull << 20));          //  8 MB bf16 partials
    unsigned short* O1    = (unsigned short*)(ws + (64ull << 20));          //  8 MB
    float* L0 = (float*)(ws + (72ull << 20));                               // 256 KB
    float* L1 = (float*)(ws + (72ull << 20) + (256ull << 10));              // 256 KB
    float2* tabQ = (float2*)(ws + (73ull << 20));                           // 512 KB
    float2* tabK = (float2*)(ws + (73ull << 20) + (512ull << 10));          // 512 KB

    cast_all_k<<<8448, 256, 0, stream>>>(x, Wq, Wk, Wv, Wo, xb, wqkvb, wob, tabQ, tabK);
    gemm_qkv_k<<<768, 256, 0, stream>>>(xb, wqkvb, tabQ, tabK, Qb, Kb, Vb);
    vtr_k<<<dim3(32, 32), 256, 0, stream>>>(Vb, Vt);
    flash_k<<<1024, 256, 0, stream>>>(Qb, Kb, Vt, O0, O1, L0, L1);
    combine_k<<<4096, 256, 0, stream>>>(O0, O1, L0, L1, Yb);
    gemm128_k<<<256, 256, 0, stream>>>(Yb, wob, out, 1024, 1024);
}